// Round 5
// baseline (100.141 us; speedup 1.0000x reference)
//
#include <hip/hip_runtime.h>

// x[B=32, C=512, H=256, W=14] f32. Per-(b,h) shuffle of the 7 same-parity
// columns (p = h%2): out[b,c,h,2j+p] = x[b,c,h,2*perm[b,h,j]+p]; other
// columns identity. Pure within-row (56 B) gather, broadcast over C.
//
// Round 5: cross-tile software pipeline, wave-private, no barriers.
//  - Block owns 4 consecutive 512-row tiles (all in one batch -> one cmap).
//  - Reg-staged T14 async-split: issue next tile's global_load_dwordx4 BEFORE
//    the current gather, ds_write to the wave's own LDS slice AFTER it.
//    Compiler derives all waitcnts (no manual vmcnt counting with stores
//    in the FIFO). Per-tile HBM drain bubble hides under gather compute.
//  - LDS = 28 KB tile + 4 KB cmap = 32 KB -> 5 blocks/CU (20 waves).
//  - cmap[h][w] = source column byte; branch-free gather.
//
//   row = flat/14; h = row & 255; b = row >> 17 (C*H = 2^17).
//   Tiles are 512 rows; 8192 tiles; batch = tile >> 8.

#define TILE_ROWS   512
#define TILE_FLOATS (TILE_ROWS * 14)   // 7168 floats = 28672 B
#define TILE_V4     (TILE_FLOATS / 4)  // 1792 float4
#define WAVE_V4     448                // float4 per wave per tile
#define TILES_PER_BLOCK 4

__global__ __launch_bounds__(256, 5) void GSRS_shuffle_pipe_kernel(
    const float* __restrict__ x,
    const int* __restrict__ perms,
    float* __restrict__ out)
{
    __shared__ float tile[TILE_FLOATS];        // 28672 B
    __shared__ unsigned char cmap[256][16];    // 4096 B  (total 32768 B)

    const unsigned tid  = threadIdx.x;
    const unsigned lane = tid & 63u;
    const unsigned wv   = tid >> 6;            // wave id 0..3
    const unsigned bid  = blockIdx.x;          // 0..2047
    const unsigned t0   = bid * TILES_PER_BLOCK;
    const unsigned b    = t0 >> 8;             // batch (256 tiles/batch)

    const unsigned q0 = wv * WAVE_V4 + lane;   // wave-private float4 base
    float4* tv = reinterpret_cast<float4*>(tile);

    // ---- prefetch tile 0 slice into regs (issued before cmap build so the
    // perm loads + VALU below cover part of the HBM latency)
    const float4* xv = reinterpret_cast<const float4*>(x);
    float4 r[7];
#pragma unroll
    for (int i = 0; i < 7; ++i)
        r[i] = xv[(size_t)t0 * TILE_V4 + q0 + i * 64];

    // ---- wave-private cmap build: lane owns rows r0, r0+1 of the wave's
    // 128-row slice; waves 0/2 (and 1/3) duplicate-write identical bytes.
    {
        const unsigned r0 = wv * 128u + 2u * lane;        // even
        const unsigned h0 = r0 & 255u;                    // even
        const int* pr = perms + b * 1792u + h0 * 7u;      // 14 consecutive ints
        int pm[14];
#pragma unroll
        for (int j = 0; j < 14; ++j) pm[j] = pr[j];
#pragma unroll
        for (int rr = 0; rr < 2; ++rr) {
            const unsigned h = h0 + rr;
            const unsigned p = h & 1u;
            union { unsigned char c[16]; uint4 v; } u;
#pragma unroll
            for (int w14 = 0; w14 < 14; ++w14) {
                unsigned src = (((unsigned)w14 & 1u) == p)
                    ? 2u * (unsigned)pm[rr * 7 + (w14 >> 1)] + p
                    : (unsigned)w14;
                u.c[w14] = (unsigned char)src;
            }
            u.c[14] = 0; u.c[15] = 0;
            *reinterpret_cast<uint4*>(&cmap[h][0]) = u.v;  // ds_write_b128
        }
    }

    // ---- commit tile-0 staging regs to the wave's LDS slice
#pragma unroll
    for (int i = 0; i < 7; ++i)
        tv[q0 + i * 64] = r[i];

    // ---- pipelined tile loop: prefetch(t+1) || gather(t) ; write(t+1)
#pragma unroll
    for (int t = 0; t < TILES_PER_BLOCK; ++t) {
        if (t + 1 < TILES_PER_BLOCK) {
#pragma unroll
            for (int i = 0; i < 7; ++i)
                r[i] = xv[(size_t)(t0 + t + 1) * TILE_V4 + q0 + i * 64];
        }

        // gather current tile from LDS, coalesced float4 store
        float4* ov = reinterpret_cast<float4*>(out) + (size_t)(t0 + t) * TILE_V4;
#pragma unroll
        for (int i = 0; i < 7; ++i) {
            const unsigned q  = q0 + i * 64;   // float4 index within tile
            unsigned lo   = q * 4u;            // float offset within tile
            unsigned lrow = lo / 14u;          // local row
            unsigned w14  = lo - lrow * 14u;
            float v[4];
#pragma unroll
            for (int k4 = 0; k4 < 4; ++k4) {
                const unsigned h   = lrow & 255u;
                const unsigned src = cmap[h][w14]; // ds_read_u8
                v[k4] = tile[lrow * 14u + src];    // ds_read_b32
                if (++w14 == 14u) { w14 = 0u; ++lrow; }
            }
            ov[q] = make_float4(v[0], v[1], v[2], v[3]);
        }

        // overwrite own slice with next tile's data; same-wave LDS program
        // order (reads above retire first) makes this barrier-free.
        if (t + 1 < TILES_PER_BLOCK) {
#pragma unroll
            for (int i = 0; i < 7; ++i)
                tv[q0 + i * 64] = r[i];
        }
    }
}

extern "C" void kernel_launch(void* const* d_in, const int* in_sizes, int n_in,
                              void* d_out, int out_size, void* d_ws, size_t ws_size,
                              hipStream_t stream) {
    const float* x     = (const float*)d_in[0];
    const int*   perms = (const int*)d_in[1];
    float*       out   = (float*)d_out;

    // 8192 tiles / 4 per block = 2048 blocks of 256 threads.
    hipLaunchKernelGGL(GSRS_shuffle_pipe_kernel, dim3(2048), dim3(256), 0, stream,
                       x, perms, out);
}

// Round 7
// 72.363 us; speedup vs baseline: 1.3839x; 1.3839x over previous
//
#include <hip/hip_runtime.h>

// x[B=32, C=512, H=256, W=14] f32. Per-(b,h) shuffle of the 7 same-parity
// columns (p = h%2): out[b,c,h,2j+p] = x[b,c,h,2*perm[b,h,j]+p]; other
// columns identity. Pure within-row (56 B) gather, broadcast over C.
//
// Round 7 = round-6 with the nontemporal-store compile fix (ext_vector type
// instead of HIP_vector_type). Structure:
//  - round-4 scaffold: 8192 blocks, wave-private, no barriers,
//    global_load_lds staging, 32 KB LDS -> 5 blocks/CU.
//  (a) perm loads issued BEFORE the DMAs (vmcnt FIFO: waiting for perm regs
//      no longer drains the DMAs) -> cmap build overlaps DMA flight;
//  (b) counted s_waitcnt vmcnt(5-i) per gather chunk: iteration i reads
//      only floats < (i+1)*256+13 of the wave slice = DMA chunks 0..i+1.
//      Gather results buffered in VGPRs so the vmem FIFO holds only DMAs
//      during the counted waits (soundness).
//  (c) nontemporal output stores: out (235 MB) stops evicting x (235 MB)
//      from the 256 MB L3 across timed replays -> reads go L3-resident.
//
//   row = flat/14; h = row & 255; b = row >> 17 (C*H = 2^17).

#define TILE_ROWS   512
#define TILE_FLOATS (TILE_ROWS * 14)   // 7168 floats = 28672 B
#define TILE_V4     (TILE_FLOATS / 4)  // 1792 float4
#define WAVE_V4     448                // float4 per wave

typedef float v4f __attribute__((ext_vector_type(4)));

#define GLOAD_LDS16(gp, lp)                                                   \
    __builtin_amdgcn_global_load_lds(                                         \
        (const __attribute__((address_space(1))) void*)(gp),                  \
        (__attribute__((address_space(3))) void*)(lp), 16, 0, 0)

__global__ __launch_bounds__(256, 5) void GSRS_shuffle_pipe7_kernel(
    const float* __restrict__ x,
    const int* __restrict__ perms,
    float* __restrict__ out)
{
    __shared__ float tile[TILE_FLOATS];        // 28672 B
    __shared__ unsigned char cmap[256][16];    // 4096 B  (total 32768 B)

    const unsigned tid  = threadIdx.x;
    const unsigned lane = tid & 63u;
    const unsigned wv   = tid >> 6;            // wave id 0..3
    const unsigned tb   = blockIdx.x;          // tile index, 0..8191
    const unsigned base = tb * TILE_FLOATS;    // float offset of tile
    const unsigned b    = tb >> 8;             // batch (256 tiles/batch)
    const unsigned q0   = wv * WAVE_V4 + lane; // wave-private float4 base

    // ---- (a) perm loads FIRST: lane owns rows r0, r0+1 (r0 even) of its
    // wave's 128-row slice; 14 consecutive ints, 8 B aligned -> 7x int2.
    const unsigned r0 = wv * 128u + 2u * lane;
    const unsigned h0 = r0 & 255u;             // even
    const int* pr = perms + b * 1792u + h0 * 7u;
    int pm[14];
#pragma unroll
    for (int j = 0; j < 7; ++j) {
        int2 t2 = *reinterpret_cast<const int2*>(pr + 2 * j);
        pm[2 * j] = t2.x; pm[2 * j + 1] = t2.y;
    }
    __builtin_amdgcn_sched_barrier(0);         // pin: perm loads older than DMAs

    // ---- issue 7 DMA chunks (each: wave-uniform LDS base + lane*16, 1 KB)
    const v4f* xv = reinterpret_cast<const v4f*>(x + base);
    v4f*       tv = reinterpret_cast<v4f*>(tile);
#pragma unroll
    for (int i = 0; i < 7; ++i)
        GLOAD_LDS16(xv + q0 + i * 64, tv + q0 + i * 64);
    __builtin_amdgcn_sched_barrier(0);         // pin: DMAs issued before cmap

    // ---- cmap build overlaps DMA flight (compiler waits only for pm regs:
    // 7 younger DMAs may stay outstanding). Waves 0/2 (1/3) write identical
    // bytes to the same entries - benign duplicate.
    {
#pragma unroll
        for (int rr = 0; rr < 2; ++rr) {
            const unsigned h = h0 + rr;
            const unsigned p = h & 1u;
            union { unsigned char c[16]; uint4 v; } u;
#pragma unroll
            for (int w14 = 0; w14 < 14; ++w14) {
                unsigned src = (((unsigned)w14 & 1u) == p)
                    ? 2u * (unsigned)pm[rr * 7 + (w14 >> 1)] + p
                    : (unsigned)w14;
                u.c[w14] = (unsigned char)src;
            }
            u.c[14] = 0; u.c[15] = 0;
            *reinterpret_cast<uint4*>(&cmap[h][0]) = u.v;  // ds_write_b128
        }
    }

    // ---- (b) gather with counted per-chunk waits; results buffered in
    // VGPRs (no stores in the vmem FIFO during the counted waits).
    v4f vbuf[7];
#pragma unroll
    for (int i = 0; i < 7; ++i) {
        if (i < 6) {
            asm volatile("s_waitcnt vmcnt(%0)" :: "i"(5 - i) : "memory");
            __builtin_amdgcn_sched_barrier(0);
        }
        const unsigned q  = q0 + i * 64;       // float4 index within tile
        unsigned lo   = q * 4u;                // float offset within tile
        unsigned lrow = lo / 14u;              // local row
        unsigned w14  = lo - lrow * 14u;
        v4f v;
#pragma unroll
        for (int k4 = 0; k4 < 4; ++k4) {
            const unsigned h   = lrow & 255u;
            const unsigned src = cmap[h][w14]; // ds_read_u8
            v[k4] = tile[lrow * 14u + src];    // ds_read_b32
            if (++w14 == 14u) { w14 = 0u; ++lrow; }
        }
        vbuf[i] = v;
    }

    // ---- (c) nontemporal coalesced stores: don't allocate out in L3.
    v4f* ov = reinterpret_cast<v4f*>(out + base);
#pragma unroll
    for (int i = 0; i < 7; ++i)
        __builtin_nontemporal_store(vbuf[i], ov + q0 + i * 64);
}

extern "C" void kernel_launch(void* const* d_in, const int* in_sizes, int n_in,
                              void* d_out, int out_size, void* d_ws, size_t ws_size,
                              hipStream_t stream) {
    const float* x     = (const float*)d_in[0];
    const int*   perms = (const int*)d_in[1];
    float*       out   = (float*)d_out;

    // 4,194,304 rows / 512 rows per tile = 8192 tiles, one block each.
    hipLaunchKernelGGL(GSRS_shuffle_pipe7_kernel, dim3(8192), dim3(256), 0, stream,
                       x, perms, out);
}

// Round 8
// 72.061 us; speedup vs baseline: 1.3897x; 1.0042x over previous
//
#include <hip/hip_runtime.h>

// x[B=32, C=512, H=256, W=14] f32. Per-(b,h) shuffle of the 7 same-parity
// columns (p = h%2): out[b,c,h,2j+p] = x[b,c,h,2*perm[b,h,j]+p]; other
// columns identity. Pure within-row (56 B) gather, broadcast over C.
//
// Round 8: bijective-window gather + full occupancy.
//  - TILE = 256 rows (one full h-cycle; tb*256 ≡ 0 mod 256 -> h = local row).
//    LDS = 14336 B tile + 4096 B cmap = 18432 B -> 8 blocks/CU, 32 waves/CU,
//    grid 16384 = exactly 8 rounds. Wave owns 64 rows = 896 floats.
//  - Gather in 64-float windows: lane l produces output float 64j+l. The
//    per-row permutation makes each window's 64 LDS reads a bijection onto a
//    contiguous ~64-word span -> ~2 lanes/bank = conflict-free (vs 8-way
//    with float4 gather; 9.1M conflict cycles in round 7).
//  - Stores: nontemporal global_store_dword, 256 B/wave contiguous.
//  - perm loads issued BEFORE the 4 DMA chunks (vmcnt FIFO: cmap build waits
//    only to vmcnt(4), DMAs stay in flight).
//  - counted waits: window j reads rows of floats <= maxin(j); chunk c covers
//    floats [224c, 224c+224) of the wave slice -> vmcnt(3)@j0, (2)@j3,
//    (1)@j7, (0)@j10.
//  - DMA chunks: 4 x 56 active lanes (224 float4 per wave), linear LDS dest.

#define TILE_ROWS   256
#define TILE_FLOATS (TILE_ROWS * 14)   // 3584 floats = 14336 B
#define WAVE_F      896                // floats per wave (64 rows)
#define WAVE_V4     224                // float4 per wave

typedef float v4f __attribute__((ext_vector_type(4)));

#define GLOAD_LDS16(gp, lp)                                                   \
    __builtin_amdgcn_global_load_lds(                                         \
        (const __attribute__((address_space(1))) void*)(gp),                  \
        (__attribute__((address_space(3))) void*)(lp), 16, 0, 0)

__global__ __launch_bounds__(256, 8) void GSRS_shuffle_win8_kernel(
    const float* __restrict__ x,
    const int* __restrict__ perms,
    float* __restrict__ out)
{
    __shared__ float tile[TILE_FLOATS];        // 14336 B
    __shared__ unsigned char cmap[256][16];    // 4096 B  (total 18432 B)

    const unsigned tid  = threadIdx.x;
    const unsigned lane = tid & 63u;
    const unsigned wv   = tid >> 6;            // wave id 0..3
    const unsigned tb   = blockIdx.x;          // tile index, 0..16383
    const unsigned base = tb * TILE_FLOATS;    // float offset of tile
    const unsigned b    = tb >> 9;             // batch (512 tiles/batch)

    // ---- perm loads FIRST (older than DMAs in the vmcnt FIFO).
    // Thread tid owns cmap row h = tid: 7 consecutive ints.
    const int* pr = perms + b * 1792u + tid * 7u;
    int pm[7];
#pragma unroll
    for (int j = 0; j < 7; ++j) pm[j] = pr[j];
    __builtin_amdgcn_sched_barrier(0);         // pin: perms older than DMAs

    // ---- issue 4 DMA chunks (56 active lanes each: 224 float4 per wave,
    // LDS dest linear = wave-uniform base + lane*16).
    const v4f* xv = reinterpret_cast<const v4f*>(x + base);
    v4f*       tv = reinterpret_cast<v4f*>(tile);
    if (lane < 56u) {
#pragma unroll
        for (int c = 0; c < 4; ++c)
            GLOAD_LDS16(xv + wv * WAVE_V4 + c * 56 + lane,
                        tv + wv * WAVE_V4 + c * 56 + lane);
    }
    __builtin_amdgcn_sched_barrier(0);         // pin: DMAs issued before cmap

    // ---- cmap build overlaps DMA flight (compiler waits vmcnt(4) for pm
    // only). Row h = tid; p = h&1; src column byte per output column.
    {
        const unsigned p = tid & 1u;
        union { unsigned char c[16]; uint4 v; } u;
#pragma unroll
        for (int w14 = 0; w14 < 14; ++w14) {
            unsigned src = (((unsigned)w14 & 1u) == p)
                ? 2u * (unsigned)pm[w14 >> 1] + p
                : (unsigned)w14;
            u.c[w14] = (unsigned char)src;
        }
        u.c[14] = 0; u.c[15] = 0;
        *reinterpret_cast<uint4*>(&cmap[tid][0]) = u.v;  // ds_write_b128
    }

    // ---- windowed gather: lane l produces slice float 64j + l.
    // Window j needs DMA chunks per maxin(j): vmcnt(3)@0, (2)@3, (1)@7, (0)@10.
    float vbuf[14];
#pragma unroll
    for (int j = 0; j < 14; ++j) {
        if (j == 0)  { asm volatile("s_waitcnt vmcnt(3)" ::: "memory");
                       __builtin_amdgcn_sched_barrier(0); }
        if (j == 3)  { asm volatile("s_waitcnt vmcnt(2)" ::: "memory");
                       __builtin_amdgcn_sched_barrier(0); }
        if (j == 7)  { asm volatile("s_waitcnt vmcnt(1)" ::: "memory");
                       __builtin_amdgcn_sched_barrier(0); }
        if (j == 10) { asm volatile("s_waitcnt vmcnt(0)" ::: "memory");
                       __builtin_amdgcn_sched_barrier(0); }
        const unsigned o    = (unsigned)j * 64u + lane;  // slice float index
        const unsigned lrow = o / 14u;                   // row within wave slice
        const unsigned w14  = o - lrow * 14u;
        const unsigned h    = wv * 64u + lrow;           // == local tile row
        const unsigned src  = cmap[h][w14];              // ds_read_u8 (same-word bcast)
        vbuf[j] = tile[h * 14u + src];                   // bijective 64-word window
    }

    // ---- nontemporal coalesced dword stores (256 B per wave-inst).
    float* op = out + base + wv * WAVE_F + lane;
#pragma unroll
    for (int j = 0; j < 14; ++j)
        __builtin_nontemporal_store(vbuf[j], op + j * 64);
}

extern "C" void kernel_launch(void* const* d_in, const int* in_sizes, int n_in,
                              void* d_out, int out_size, void* d_ws, size_t ws_size,
                              hipStream_t stream) {
    const float* x     = (const float*)d_in[0];
    const int*   perms = (const int*)d_in[1];
    float*       out   = (float*)d_out;

    // 4,194,304 rows / 256 rows per tile = 16384 tiles, one block each.
    hipLaunchKernelGGL(GSRS_shuffle_win8_kernel, dim3(16384), dim3(256), 0, stream,
                       x, perms, out);
}